// Round 1
// baseline (360.915 us; speedup 1.0000x reference)
//
#include <hip/hip_runtime.h>

// CRF forward: B=512, T=1024, N=64. fwd/bwd split, one wave per chain.
// Round 11: SGPR-BROADCAST matvec (replaces LDS broadcast).
// Round-10 profile: VALUBusy 15%, ~708 cyc/step vs ~260 cyc of issued work.
// Diagnosis: the per-step a-vector broadcast via 16x ds_read_b128 returns
// 16 KiB/step/wave (per-lane bandwidth, even though all lanes read the same
// 256 B); 4 waves/CU share ~128 B/cyc LDS read BW => ~512 cyc/step of LDS
// serialization. Fix: broadcast via v_readlane -> SGPR and consume as the
// free scalar operand of v_fma_f32. Zero LDS traffic in the loop, no DS
// latency on the chain, no cross-wave contention. Per step:
//   64 v_readlane + 64 v_fma (4 accumulator chains) + 3 adds + 1 mul.
// Exp-domain recurrence with exact exponent-only rescale every 4 steps
// (unchanged from round 10):
//   a'_j = (sum_i a_i E_ij) * w_j,  w_j = exp(u_t[j]) precomputed off-chain
//   out  = ln2 * (off_f + off_b + log2(sum_i a_i b_i)).

typedef float f4 __attribute__((ext_vector_type(4)));

constexpr int Tt = 1024;
constexpr int Nn = 64;
constexpr int ES = 68;  // f32 row stride for E staging: 272 B, 16B-aligned
constexpr float LN2 = 0.69314718055994530942f;

__device__ __forceinline__ float rlane(float v, int l) {
    return __uint_as_float(
        (unsigned)__builtin_amdgcn_readlane((int)__float_as_uint(v), l));
}

__global__ __launch_bounds__(128, 1) void crf_fwd(
    const float* __restrict__ unary,
    const int*   __restrict__ lengths,
    const float* __restrict__ trans,
    float*       __restrict__ out)
{
    const int b    = blockIdx.x;
    const int tid  = threadIdx.x;
    const int w    = tid >> 6;   // 0 = forward wave, 1 = backward wave
    const int lane = tid & 63;

    __shared__ float Ecol[Nn * ES];   // Ecol[j*ES+i] = exp(trans[i][j])
    __shared__ float Erow[Nn * ES];   // Erow[i*ES+j] = exp(trans[i][j])
    __shared__ float shb[Nn];         // beta at midpoint (combine)
    __shared__ int   sh_off_b;        // bwd exponent offset

    // One-time staging of E = exp(trans), both orientations (transpose
    // for the fwd wave's column access). Off the hot loop entirely.
    #pragma unroll
    for (int c = 0; c < (Nn * Nn) / 128; ++c) {
        int idx = c * 128 + tid;
        int i = idx >> 6, j = idx & 63;
        float e = __expf(trans[idx]);
        Erow[i * ES + j] = e;
        Ecol[j * ES + i] = e;
    }
    __syncthreads();

    // Lane's 64 E values in registers (fwd: column `lane`; bwd: row `lane`).
    const f4* eb = (const f4*)((w == 0) ? &Ecol[lane * ES] : &Erow[lane * ES]);
    f4 Ev[16];
    #pragma unroll
    for (int r = 0; r < 16; ++r) Ev[r] = eb[r];

    int L = lengths[b];
    L = L < 1 ? 1 : (L > Tt ? Tt : L);
    const int m = (L - 1) >> 1;

    const float* ub = unary + (size_t)b * Tt * Nn;

    const int trips = (w == 0) ? m : (L - 1 - m);
    const int tbase = (w == 0) ? 1 : (L - 1);
    const int dir   = (w == 0) ? 1 : -1;

    // Exp-domain state + exponent offset.
    float acc = (w == 0) ? __expf(ub[lane]) : 1.0f;
    int   off = 0;

    // 4-deep prefetch of w_t = exp(u_t) (loads + exps are all off-chain).
    float w_cur[4];
    {
        int smax = trips > 0 ? trips - 1 : 0;
        #pragma unroll
        for (int k = 0; k < 4; ++k) {
            int sc = k < smax ? k : smax;
            w_cur[k] = __expf(ub[(tbase + dir * sc) * Nn + lane]);
        }
    }

    for (int s0 = 0; s0 < trips; s0 += 4) {
        float w_nxt[4];
        #pragma unroll
        for (int k = 0; k < 4; ++k) {
            int sc = s0 + 4 + k;
            if (sc > trips - 1) sc = trips - 1;
            w_nxt[k] = __expf(ub[(tbase + dir * sc) * Nn + lane]);
        }

        #pragma unroll
        for (int k = 0; k < 4; ++k) {
            if (s0 + k >= trips) break;  // wave-uniform

            // fwd: a' = (E^T a) * w   (w on output)
            // bwd: a' = E (w * a)     (w on input)
            float src = (w != 0) ? acc * w_cur[k] : acc;

            // SGPR-broadcast matvec: z_lane = sum_i src_i * Ev[i].
            // v_readlane -> SGPR; v_fma_f32 reads it as its one scalar
            // operand. 4 independent accumulator chains for ILP.
            float z0 = 0.f, z1 = 0.f, z2 = 0.f, z3 = 0.f;
            #pragma unroll
            for (int r = 0; r < 16; ++r) {
                float a0 = rlane(src, 4 * r + 0);
                float a1 = rlane(src, 4 * r + 1);
                float a2 = rlane(src, 4 * r + 2);
                float a3 = rlane(src, 4 * r + 3);
                z0 = __builtin_fmaf(a0, Ev[r].x, z0);
                z1 = __builtin_fmaf(a1, Ev[r].y, z1);
                z2 = __builtin_fmaf(a2, Ev[r].z, z2);
                z3 = __builtin_fmaf(a3, Ev[r].w, z3);
            }
            float z = (z0 + z1) + (z2 + z3);

            acc = (w == 0) ? z * w_cur[k] : z;
        }

        // Exact exponent-only rescale (once per 4 steps; keeps fp32 in
        // range: worst drift 4 steps * ~14 bits + ~10 bits lane spread).
        {
            unsigned s0b = (unsigned)__builtin_amdgcn_readfirstlane(
                (int)__float_as_uint(acc));
            int e = (int)((s0b >> 23) & 0xFF) - 127;
            off += e;
            acc *= __uint_as_float((unsigned)(127 - e) << 23);
        }

        #pragma unroll
        for (int k = 0; k < 4; ++k) w_cur[k] = w_nxt[k];
    }

    // Combine: out[b] = ln2 * (off_f + off_b + log2(sum_i a_i * b_i)).
    if (w == 1) {
        shb[lane] = acc;
        if (lane == 0) sh_off_b = off;
    }
    __syncthreads();
    if (w == 0) {
        float v = acc * shb[lane];
        float ssum = v;
        #pragma unroll
        for (int k = 32; k >= 1; k >>= 1)
            ssum += __shfl_xor(ssum, k, 64);
        if (lane == 0) {
            float l2 = __builtin_amdgcn_logf(ssum);  // v_log_f32 = log2
            out[b] = LN2 * ((float)(off + sh_off_b) + l2);
        }
    }
}

extern "C" void kernel_launch(void* const* d_in, const int* in_sizes, int n_in,
                              void* d_out, int out_size, void* d_ws, size_t ws_size,
                              hipStream_t stream) {
    const float* unary   = (const float*)d_in[0];
    const int*   lengths = (const int*)d_in[1];
    const float* trans   = (const float*)d_in[2];
    float*       out     = (float*)d_out;

    const int Bb = in_sizes[1];  // 512
    crf_fwd<<<Bb, 128, 0, stream>>>(unary, lengths, trans, out);
}

// Round 2
// 356.780 us; speedup vs baseline: 1.0116x; 1.0116x over previous
//
#include <hip/hip_runtime.h>

// CRF forward: B=512, T=1024, N=64. fwd/bwd split, one wave per chain.
// Round 12: PARTIAL-OUTPUT matvec with DPP row-gather (no per-step broadcast).
// History: round-10 LDS broadcast = 708 cyc/step (64x ds_read_b128/CU/step on
// the shared LDS pipe @ ~12cyc each); round-11 readlane = ~1000 cyc/step
// (VALU->SGPR->VALU hazard chain). Both pay for a full 64-value all-to-all.
// Fix: lane j (row r=j>>4, pos p=j&15) computes partials for the 4 outputs
// {p+16g} over inputs i in row r ONLY:
//   P[g] = sum_m a_{16r+(p^s_m)} * M[p+16g][16r+(p^s_m)]
// The row gather is 15 DPP movs with XOR-only controls (sign-unambiguous):
//   quad_perm[1,0,3,2]=xor1, quad_perm[2,3,0,1]=xor2,
//   row_half_mirror=xor7, row_ror:8=xor8  (s_m = XOR of selected masks).
// Reduce across the 4-lane group {p+16r}: permlane32_swap pair-sum (robust
// to either swap orientation: swap(x,copy) yields {lo-rep,hi-rep} in SOME
// order; we only ADD them) + ds_swizzle xor16 + add. E is pre-permuted
// per lane at load so the gathered order lines up. LDS pipe per step: 4
// ds_swizzle_b32 total (vs 64 b128 reads in round 10).
// Exp-domain recurrence + exponent-only rescale every 4 steps (unchanged).

typedef float f2 __attribute__((ext_vector_type(2)));

constexpr int Tt = 1024;
constexpr int Nn = 64;
constexpr int ES = 68;  // f32 row stride for E staging (one-time scatter)
constexpr float LN2 = 0.69314718055994530942f;

template<int CTRL>
__device__ __forceinline__ float dppf(float x) {
    return __uint_as_float((unsigned)__builtin_amdgcn_update_dpp(
        0, (int)__float_as_uint(x), CTRL, 0xF, 0xF, false));
}

// lane L gets value of lane L^16 (within each 32-lane group).
__device__ __forceinline__ float swz16(float x) {
    return __uint_as_float((unsigned)__builtin_amdgcn_ds_swizzle(
        (int)__float_as_uint(x), 0x401F));
}

// Pair-sum across the 32-lane halves: returns (lo-half value + hi-half
// value), replicated. swap(x, copy(x)) produces {lo-rep, hi-rep} in an
// orientation-dependent order; adding both is order-robust.
// s_nop 1 guards the VALU-write -> cross-lane-read hazard (inline asm is
// opaque to the compiler's hazard mitigation).
__device__ __forceinline__ float xsum32(float x) {
    float a = x, b = x;
    asm("s_nop 1\n\tv_permlane32_swap_b32 %0, %1" : "+v"(a), "+v"(b));
    return a + b;
}

__global__ __launch_bounds__(128, 1) void crf_fwd(
    const float* __restrict__ unary,
    const int*   __restrict__ lengths,
    const float* __restrict__ trans,
    float*       __restrict__ out)
{
    const int b    = blockIdx.x;
    const int tid  = threadIdx.x;
    const int w    = tid >> 6;   // 0 = forward wave, 1 = backward wave
    const int lane = tid & 63;
    const int p    = lane & 15;
    const int r    = lane >> 4;

    __shared__ float Erow[Nn * ES];   // Erow[i*ES+j] = exp(trans[i][j])
    __shared__ float shb[Nn];         // beta at midpoint (combine)
    __shared__ int   sh_off_b;        // bwd exponent offset

    // One-time staging of E = exp(trans) (row-major only; per-lane permuted
    // gather below handles both orientations).
    #pragma unroll
    for (int c = 0; c < (Nn * Nn) / 128; ++c) {
        int idx = c * 128 + tid;
        Erow[(idx >> 6) * ES + (idx & 63)] = __expf(trans[idx]);
    }
    __syncthreads();

    // Per-lane E fragment, permuted to the DPP gather order.
    // m -> s_m: XOR of masks {1,2,7,8} selected by m's bits.
    // fwd: M[o][i] = E[i][o] (a' = E^T a); bwd: M[o][i] = E[o][i].
    f2 E2[4][8];
    #pragma unroll
    for (int g = 0; g < 4; ++g) {
        #pragma unroll
        for (int m = 0; m < 16; ++m) {
            int s = ((m & 1) ? 1 : 0) ^ ((m & 2) ? 2 : 0)
                  ^ ((m & 4) ? 7 : 0) ^ ((m & 8) ? 8 : 0);
            int i = 16 * r + (p ^ s);
            int o = p + 16 * g;
            E2[g][m >> 1][m & 1] =
                (w == 0) ? Erow[i * ES + o] : Erow[o * ES + i];
        }
    }

    int L = lengths[b];
    L = L < 1 ? 1 : (L > Tt ? Tt : L);
    const int m2 = (L - 1) >> 1;

    const float* ub = unary + (size_t)b * Tt * Nn;

    const int trips = (w == 0) ? m2 : (L - 1 - m2);
    const int tbase = (w == 0) ? 1 : (L - 1);
    const int dir   = (w == 0) ? 1 : -1;

    // Exp-domain state + exponent offset.
    float acc = (w == 0) ? __expf(ub[lane]) : 1.0f;
    int   off = 0;

    // 4-deep prefetch of w_t = exp(u_t) (loads + exps are all off-chain).
    float w_cur[4];
    {
        int smax = trips > 0 ? trips - 1 : 0;
        #pragma unroll
        for (int k = 0; k < 4; ++k) {
            int sc = k < smax ? k : smax;
            w_cur[k] = __expf(ub[(tbase + dir * sc) * Nn + lane]);
        }
    }

    for (int s0 = 0; s0 < trips; s0 += 4) {
        float w_nxt[4];
        #pragma unroll
        for (int k = 0; k < 4; ++k) {
            int sc = s0 + 4 + k;
            if (sc > trips - 1) sc = trips - 1;
            w_nxt[k] = __expf(ub[(tbase + dir * sc) * Nn + lane]);
        }

        #pragma unroll
        for (int k = 0; k < 4; ++k) {
            if (s0 + k >= trips) break;  // wave-uniform

            // fwd: a' = (E^T a) * w   (w on output)
            // bwd: a' = E (w * a)     (w on input)
            float src = (w != 0) ? acc * w_cur[k] : acc;

            // DPP row-gather: gp[q] = (a at pos p^s_{2q}, a at pos p^s_{2q+1}).
            f2 gp[8];
            gp[0][0] = src;                    // s=0
            gp[0][1] = dppf<0xB1>(gp[0][0]);   // s=1  quad_perm [1,0,3,2]
            gp[1][0] = dppf<0x4E>(gp[0][0]);   // s=2  quad_perm [2,3,0,1]
            gp[1][1] = dppf<0x4E>(gp[0][1]);   // s=3
            gp[2][0] = dppf<0x141>(gp[0][0]);  // s=7  row_half_mirror
            gp[2][1] = dppf<0x141>(gp[0][1]);  // s=6
            gp[3][0] = dppf<0x141>(gp[1][0]);  // s=5
            gp[3][1] = dppf<0x141>(gp[1][1]);  // s=4
            gp[4][0] = dppf<0x128>(gp[0][0]);  // s=8  row_ror:8 (== xor8)
            gp[4][1] = dppf<0x128>(gp[0][1]);  // s=9
            gp[5][0] = dppf<0x128>(gp[1][0]);  // s=10
            gp[5][1] = dppf<0x128>(gp[1][1]);  // s=11
            gp[6][0] = dppf<0x128>(gp[2][0]);  // s=15
            gp[6][1] = dppf<0x128>(gp[2][1]);  // s=14
            gp[7][0] = dppf<0x128>(gp[3][0]);  // s=13
            gp[7][1] = dppf<0x128>(gp[3][1]);  // s=12

            // Partials: P[g] = sum over own row (2 pk_fma chains, depth 4).
            f2 aA[4], aB[4];
            #pragma unroll
            for (int g = 0; g < 4; ++g) {
                aA[g] = (f2){0.f, 0.f};
                aB[g] = (f2){0.f, 0.f};
                #pragma unroll
                for (int q = 0; q < 8; q += 2) {
                    aA[g] = gp[q]     * E2[g][q]     + aA[g];
                    aB[g] = gp[q + 1] * E2[g][q + 1] + aB[g];
                }
            }

            // Cross-row reduce: stride-32 (permlane pair-sum) then stride-16
            // (swizzle xor16). Result replicated over each 4-lane group.
            float s1[4];
            #pragma unroll
            for (int g = 0; g < 4; ++g) {
                f2 t = aA[g] + aB[g];
                s1[g] = xsum32(t[0] + t[1]);
            }
            float sw[4];
            #pragma unroll
            for (int g = 0; g < 4; ++g) sw[g] = swz16(s1[g]);

            float z0 = s1[0] + sw[0], z1 = s1[1] + sw[1];
            float z2 = s1[2] + sw[2], z3 = s1[3] + sw[3];
            // Keep the group with g == own row r (r bits: lane&16, lane&32).
            float zl = (lane & 16) ? z1 : z0;
            float zh = (lane & 16) ? z3 : z2;
            float z  = (lane & 32) ? zh : zl;

            acc = (w == 0) ? z * w_cur[k] : z;
        }

        // Exact exponent-only rescale (once per 4 steps; keeps fp32 in
        // range: worst drift 4 steps * ~14 bits + ~10 bits lane spread).
        {
            unsigned s0b = (unsigned)__builtin_amdgcn_readfirstlane(
                (int)__float_as_uint(acc));
            int e = (int)((s0b >> 23) & 0xFF) - 127;
            off += e;
            acc *= __uint_as_float((unsigned)(127 - e) << 23);
        }

        #pragma unroll
        for (int k = 0; k < 4; ++k) w_cur[k] = w_nxt[k];
    }

    // Combine: out[b] = ln2 * (off_f + off_b + log2(sum_i a_i * b_i)).
    if (w == 1) {
        shb[lane] = acc;
        if (lane == 0) sh_off_b = off;
    }
    __syncthreads();
    if (w == 0) {
        float v = acc * shb[lane];
        float ssum = v;
        #pragma unroll
        for (int k = 32; k >= 1; k >>= 1)
            ssum += __shfl_xor(ssum, k, 64);
        if (lane == 0) {
            float l2 = __builtin_amdgcn_logf(ssum);  // v_log_f32 = log2
            out[b] = LN2 * ((float)(off + sh_off_b) + l2);
        }
    }
}

extern "C" void kernel_launch(void* const* d_in, const int* in_sizes, int n_in,
                              void* d_out, int out_size, void* d_ws, size_t ws_size,
                              hipStream_t stream) {
    const float* unary   = (const float*)d_in[0];
    const int*   lengths = (const int*)d_in[1];
    const float* trans   = (const float*)d_in[2];
    float*       out     = (float*)d_out;

    const int Bb = in_sizes[1];  // 512
    crf_fwd<<<Bb, 128, 0, stream>>>(unary, lengths, trans, out);
}